// Round 2
// 288.830 us; speedup vs baseline: 1.0354x; 1.0354x over previous
//
#include <hip/hip_runtime.h>

#define BN_EPS 1e-5f
#define NBLK 1024   // kernel-1 blocks; each owns 64 samples

typedef float f4v __attribute__((ext_vector_type(4)));

// ---------------------------------------------------------------------------
// Kernel 1: fused encode + sim + linear + per-block BN partials.
// Block b owns samples [b*64, b*64+64):
//   phase 1: 4 waves encode 16 samples each; 4-sample software pipeline:
//            16 nontemporal dwordx4 loads issued before any reduce (MLP),
//            then shuffle-reduce each sample -> LDS
//   phase 2: lanes of wave 0 sim one sample each, out -> global ws,
//            wave-reduced sum/sumsq -> partials[b][8]  (no atomics)
// ---------------------------------------------------------------------------
__global__ __launch_bounds__(256) void encode_sim_kernel(
    const float* __restrict__ x,
    const float* __restrict__ params,
    const float* __restrict__ Wm,
    const float* __restrict__ bvec,
    float* __restrict__ out_ws,
    float* __restrict__ partials) {
    __shared__ float G[96];        // 12 gates x 8 floats
    __shared__ float encl[64][5];  // stride 5 -> conflict-free

    const int tid  = threadIdx.x;
    const int lane = tid & 63;
    const int wv   = tid >> 6;
    const int b    = blockIdx.x;
    const int base = b * 64;

    // gates: M[l,w] = RX(t1) @ RZ(t0)
    if (tid < 12) {
        float t0 = params[tid * 3 + 0];
        float t1 = params[tid * 3 + 1];
        float s0, c0, s1, c1;
        __sincosf(0.5f * t0, &s0, &c0);
        __sincosf(0.5f * t1, &s1, &c1);
        float* m = G + tid * 8;
        m[0] = c1 * c0;   m[1] = -c1 * s0;   // M00 = cx*ez
        m[2] = s1 * s0;   m[3] = -s1 * c0;   // M01 = sx*ezc
        m[4] = -s1 * s0;  m[5] = -s1 * c0;   // M10 = sx*ez
        m[6] = c1 * c0;   m[7] = c1 * s0;    // M11 = cx*ezc
    }

    // ---- phase 1: encode (4 waves x 16 samples, 4-sample pipeline) ----
    const f4v* xbase = (const f4v*)(x + (size_t)base * 784);
    const f4v zero4 = 0.f;
    for (int i0 = 0; i0 < 16; i0 += 4) {
        f4v v[4][4];
#pragma unroll
        for (int u = 0; u < 4; u++) {
            const int sl = wv * 16 + i0 + u;
            const f4v* xs = xbase + (size_t)sl * 196;  // 784 floats = 196 f4v
            v[u][0] = __builtin_nontemporal_load(xs + lane);
            v[u][1] = __builtin_nontemporal_load(xs + 64 + lane);
            v[u][2] = __builtin_nontemporal_load(xs + 128 + lane);
            v[u][3] = (lane < 4) ? __builtin_nontemporal_load(xs + 192 + lane)
                                 : zero4;
        }
#pragma unroll
        for (int u = 0; u < 4; u++) {
            const int sl = wv * 16 + i0 + u;
            float t0 = (v[u][0].x + v[u][0].y) + (v[u][0].z + v[u][0].w);
            float t1 = (v[u][1].x + v[u][1].y) + (v[u][1].z + v[u][1].w);
            float t2 = (v[u][2].x + v[u][2].y) + (v[u][2].z + v[u][2].w);
            float t3 = (v[u][3].x + v[u][3].y) + (v[u][3].z + v[u][3].w);

            // group g = f/49 boundaries at float4 idx 49, 98, 147
            float s0 = (lane < 49) ? t0 : 0.f;
            float s1 = ((lane >= 49) ? t0 : 0.f) + ((lane < 34) ? t1 : 0.f);
            float s2 = ((lane >= 34) ? t1 : 0.f) + ((lane < 19) ? t2 : 0.f);
            float s3 = ((lane >= 19) ? t2 : 0.f) + t3;

#pragma unroll
            for (int off = 32; off > 0; off >>= 1) {
                s0 += __shfl_down(s0, off);
                s1 += __shfl_down(s1, off);
                s2 += __shfl_down(s2, off);
                s3 += __shfl_down(s3, off);
            }
            if (lane == 0) {
                const float inv = 1.0f / 196.0f;
                encl[sl][0] = s0 * inv;
                encl[sl][1] = s1 * inv;
                encl[sl][2] = s2 * inv;
                encl[sl][3] = s3 * inv;
            }
        }
    }
    __syncthreads();

    // ---- phase 2: sim (wave 0 only, one sample per lane) ----
    if (wv == 0) {
        float ang[4] = {encl[lane][0], encl[lane][1], encl[lane][2], encl[lane][3]};
        float cw[4], sw[4];
#pragma unroll
        for (int w = 0; w < 4; w++) __sincosf(0.5f * ang[w], &sw[w], &cw[w]);

        float sr[16], si[16];
#pragma unroll
        for (int i = 0; i < 16; i++) { sr[i] = 0.f; si[i] = 0.f; }
        sr[0] = 1.0f;

#pragma unroll
        for (int l = 0; l < 3; l++) {
#pragma unroll
            for (int w = 0; w < 4; w++) {
                const float* m = G + (l * 4 + w) * 8;
                float c = cw[w], s = sw[w];
                // U = M @ RY, RY = [[c,-s],[s,c]]
                float u00r = m[0] * c + m[2] * s;
                float u00i = m[1] * c + m[3] * s;
                float u01r = -m[0] * s + m[2] * c;
                float u01i = -m[1] * s + m[3] * c;
                float u10r = m[4] * c + m[6] * s;
                float u10i = m[5] * c + m[7] * s;
                float u11r = -m[4] * s + m[6] * c;
                float u11i = -m[5] * s + m[7] * c;
                const int stride = 8 >> w;
#pragma unroll
                for (int i = 0; i < 16; i++) {
                    if (i & stride) continue;
                    int j = i | stride;
                    float a0r = sr[i], a0i = si[i];
                    float a1r = sr[j], a1i = si[j];
                    sr[i] = u00r * a0r - u00i * a0i + u01r * a1r - u01i * a1i;
                    si[i] = u00r * a0i + u00i * a0r + u01r * a1i + u01i * a1r;
                    sr[j] = u10r * a0r - u10i * a0i + u11r * a1r - u11i * a1i;
                    si[j] = u10r * a0i + u10i * a0r + u11r * a1i + u11i * a1r;
                }
                if (w < 3) {  // CNOT(control=w, target=w+1)
                    const int ts = 8 >> (w + 1);
#pragma unroll
                    for (int i = 0; i < 16; i++) {
                        if (!(i & stride)) continue;
                        if (i & ts) continue;
                        int j = i | ts;
                        float tr = sr[i]; sr[i] = sr[j]; sr[j] = tr;
                        float ti = si[i]; si[i] = si[j]; si[j] = ti;
                    }
                }
            }
        }

        float p[16];
#pragma unroll
        for (int i = 0; i < 16; i++) p[i] = sr[i] * sr[i] + si[i] * si[i];
        float z[4];
#pragma unroll
        for (int w = 0; w < 4; w++) {
            const int stride = 8 >> w;
            float acc = 0.f;
#pragma unroll
            for (int i = 0; i < 16; i++) acc += (i & stride) ? -p[i] : p[i];
            z[w] = acc;
        }

        float o[4];
#pragma unroll
        for (int j = 0; j < 4; j++) {
            o[j] = bvec[j] + Wm[j * 4 + 0] * z[0] + Wm[j * 4 + 1] * z[1] +
                   Wm[j * 4 + 2] * z[2] + Wm[j * 4 + 3] * z[3];
        }
        ((float4*)out_ws)[base + lane] = make_float4(o[0], o[1], o[2], o[3]);

        // per-block BN partials (8 values) via wave reduce, no atomics
        float vals[8];
#pragma unroll
        for (int j = 0; j < 4; j++) { vals[j] = o[j]; vals[4 + j] = o[j] * o[j]; }
#pragma unroll
        for (int k = 0; k < 8; k++) {
#pragma unroll
            for (int off = 32; off > 0; off >>= 1) vals[k] += __shfl_down(vals[k], off);
        }
        if (lane == 0) {
#pragma unroll
            for (int k = 0; k < 8; k++) partials[b * 8 + k] = vals[k];
        }
    }
}

// ---------------------------------------------------------------------------
// Kernel 2: reduce partials[NBLK][8] (every block, L2-resident), BN finalize,
// normalize. One thread per sample.
// ---------------------------------------------------------------------------
__global__ __launch_bounds__(256) void norm_kernel(
    const float* __restrict__ out_ws,
    const float* __restrict__ partials,
    const float* __restrict__ bn_w,
    const float* __restrict__ bn_b,
    float* __restrict__ dout,
    float inv_batch) {
    __shared__ float red[32][8];
    __shared__ float scsh[8];
    const int tid = threadIdx.x;

    {
        int f = tid & 7, row = tid >> 3;  // 32 rows x 8 features
        float acc = 0.f;
#pragma unroll 4
        for (int i = 0; i < NBLK / 32; i++) acc += partials[(row + 32 * i) * 8 + f];
        red[row][f] = acc;
    }
    __syncthreads();
    if (tid < 8) {
        float t = 0.f;
#pragma unroll
        for (int r = 0; r < 32; r++) t += red[r][tid];
        red[0][tid] = t;  // sums8
    }
    __syncthreads();
    if (tid < 4) {
        float mu = red[0][tid] * inv_batch;
        float ex2 = red[0][tid + 4] * inv_batch;
        float var = ex2 - mu * mu;
        float s = bn_w[tid] * rsqrtf(var + BN_EPS);
        scsh[tid] = s;
        scsh[4 + tid] = bn_b[tid] - mu * s;
    }
    __syncthreads();

    int t = blockIdx.x * blockDim.x + tid;
    float4 o = ((const float4*)out_ws)[t];
    ((float4*)dout)[t] = make_float4(o.x * scsh[0] + scsh[4],
                                     o.y * scsh[1] + scsh[5],
                                     o.z * scsh[2] + scsh[6],
                                     o.w * scsh[3] + scsh[7]);
}

extern "C" void kernel_launch(void* const* d_in, const int* in_sizes, int n_in,
                              void* d_out, int out_size, void* d_ws, size_t ws_size,
                              hipStream_t stream) {
    const float* x      = (const float*)d_in[0];  // (B,1,28,28)
    const float* params = (const float*)d_in[1];  // (3,4,3)
    const float* Wm     = (const float*)d_in[2];  // (4,4)
    const float* bvec   = (const float*)d_in[3];  // (4,)
    const float* bn_w   = (const float*)d_in[4];  // (4,)
    const float* bn_b   = (const float*)d_in[5];  // (4,)
    float* dout = (float*)d_out;

    const int B = in_sizes[0] / 784;  // 65536

    float* ws       = (float*)d_ws;
    float* partials = ws;                    // NBLK*8 floats
    float* outw     = ws + NBLK * 8;         // B*4 floats (32KB offset, 16B aligned)

    encode_sim_kernel<<<NBLK, 256, 0, stream>>>(x, params, Wm, bvec, outw, partials);
    norm_kernel<<<B / 256, 256, 0, stream>>>(outw, partials, bn_w, bn_b, dout,
                                             1.0f / (float)B);
}